// Round 2
// baseline (29991.321 us; speedup 1.0000x reference)
//
#include <hip/hip_runtime.h>
#include <stdint.h>

// ============================================================================
// CharNN: 2-layer GRU char LM (B=64, T=512, V=256, E=H=1024) on MI355X.
// Round 2 strategy (crash fix = ws_size-adaptive small footprint):
//  * G0 trick: layer-1 input GEMM = gather of precomputed (emb @ W_ih0^T + b_ih0)
//  * split-bf16 (hi+lo) MFMA, split computed IN-KERNEL from fp32 operands
//    (same global bytes as pre-split storage, zero arena cost)
//  * chunked pipeline over T: y1c/y2c fp32 chunk buffers double as the h-chain
//  * footprint = 3 MB + Tc*1.25 MB, Tc picked at runtime from ws_size
//  * gru_step: 64 blocks x 256 thr, register prefetch across the LDS barrier
// ============================================================================

namespace {

constexpr int B = 64, T = 512, V = 256, H = 1024, G = 3072; // G = 3*H

typedef short bf16x8 __attribute__((ext_vector_type(8)));
typedef float f32x4 __attribute__((ext_vector_type(4)));

__device__ __forceinline__ unsigned short f2bf(float f) {
  unsigned int u = __float_as_uint(f);
  u += 0x7fffu + ((u >> 16) & 1u);           // round-to-nearest-even
  return (unsigned short)(u >> 16);
}
__device__ __forceinline__ float bf2f(unsigned short h) {
  return __uint_as_float(((unsigned int)h) << 16);
}

// split 8 floats (two float4 regs) into hi/lo bf16 int4 packs
__device__ __forceinline__ void split8(float4 f0, float4 f1, int4& hv, int4& lv) {
  float vv[8] = {f0.x, f0.y, f0.z, f0.w, f1.x, f1.y, f1.z, f1.w};
  union { unsigned short u[8]; int4 v; } uh, ul;
#pragma unroll
  for (int q = 0; q < 8; ++q) {
    unsigned short hb = f2bf(vv[q]);
    uh.u[q] = hb;
    ul.u[q] = f2bf(vv[q] - bf2f(hb));
  }
  hv = uh.v; lv = ul.v;
}

// ---- split-bf16 GEMM: C[M,N] = A[M,K] @ B[N,K]^T + bias --------------------
// A,B fp32, split in-kernel. 3-term MFMA => ~fp32 accuracy.
// MODE 0: C fp32 row-major [M,N].
// MODE 2: logits epilogue. Local row m = i*64+b (chunk [Tc,B,H] order);
//         global t = tc+i; write out[(b*(T-1)+t)*V + n] for t<T-1. N==V.
template <int MODE>
__global__ __launch_bounds__(256) void gemm_bt_f32(
    const float* __restrict__ A, const float* __restrict__ Bm,
    const float* __restrict__ bias, float* __restrict__ C,
    int M, int N, int K, int tc) {
  __shared__ __align__(16) unsigned short Ah[64][40], Al[64][40];
  __shared__ __align__(16) unsigned short Bh[64][40], Bl[64][40];

  const int tid = threadIdx.x;
  const int lane = tid & 63, wv = tid >> 6;
  const int bm = blockIdx.y, bn = blockIdx.x;
  const int srow = tid >> 2;            // 0..63
  const int sseg = (tid & 3) * 8;       // 0,8,16,24

  const float* pA = A + (size_t)(bm * 64 + srow) * K + sseg;
  const float* pB = Bm + (size_t)(bn * 64 + srow) * K + sseg;

  f32x4 acc[4];
  const f32x4 zero = {0.f, 0.f, 0.f, 0.f};
#pragma unroll
  for (int nt = 0; nt < 4; ++nt) acc[nt] = zero;

  const int ar = wv * 16 + (lane & 15);
  const int kk = (lane >> 4) * 8;

  for (int k0 = 0; k0 < K; k0 += 32) {
    float4 a0 = *reinterpret_cast<const float4*>(pA + k0);
    float4 a1 = *reinterpret_cast<const float4*>(pA + k0 + 4);
    float4 b0 = *reinterpret_cast<const float4*>(pB + k0);
    float4 b1 = *reinterpret_cast<const float4*>(pB + k0 + 4);
    int4 hA, lA, hB, lB;
    split8(a0, a1, hA, lA);
    split8(b0, b1, hB, lB);
    __syncthreads();
    *reinterpret_cast<int4*>(&Ah[srow][sseg]) = hA;
    *reinterpret_cast<int4*>(&Al[srow][sseg]) = lA;
    *reinterpret_cast<int4*>(&Bh[srow][sseg]) = hB;
    *reinterpret_cast<int4*>(&Bl[srow][sseg]) = lB;
    __syncthreads();

    bf16x8 ah = *reinterpret_cast<const bf16x8*>(&Ah[ar][kk]);
    bf16x8 al = *reinterpret_cast<const bf16x8*>(&Al[ar][kk]);
#pragma unroll
    for (int nt = 0; nt < 4; ++nt) {
      const int br = nt * 16 + (lane & 15);
      bf16x8 bh = *reinterpret_cast<const bf16x8*>(&Bh[br][kk]);
      bf16x8 bl = *reinterpret_cast<const bf16x8*>(&Bl[br][kk]);
      acc[nt] = __builtin_amdgcn_mfma_f32_16x16x32_bf16(ah, bh, acc[nt], 0, 0, 0);
      acc[nt] = __builtin_amdgcn_mfma_f32_16x16x32_bf16(ah, bl, acc[nt], 0, 0, 0);
      acc[nt] = __builtin_amdgcn_mfma_f32_16x16x32_bf16(al, bh, acc[nt], 0, 0, 0);
    }
  }

  // C/D layout (m89-verified): col = lane&15, row = (lane>>4)*4 + reg
  const int rbase = wv * 16 + (lane >> 4) * 4;
  const int cl = lane & 15;
#pragma unroll
  for (int nt = 0; nt < 4; ++nt) {
    const int n = bn * 64 + nt * 16 + cl;
    const float bv = bias[n];
#pragma unroll
    for (int r = 0; r < 4; ++r) {
      const int m = bm * 64 + rbase + r;
      const float v = acc[nt][r] + bv;
      if (MODE == 0) {
        C[(size_t)m * N + n] = v;
      } else {
        const int i = m >> 6, bb = m & 63;  // chunk-local [i,b]
        const int t = tc + i;
        if (t < T - 1) C[((size_t)(bb * (T - 1) + t)) * V + n] = v;
      }
    }
  }
}

// ---- one GRU step (one layer, one t) ---------------------------------------
// h_in fp32 [64,1024]; Whh fp32 layer slice [3072,1024]; b_hh fp32 [3072].
// gx: layer1 -> G0 fp32 [256,3072] row-selected by xrow[b*T] (xrow = X + t);
//     layer2 -> gx_base fp32 with row stride G per batch (xrow = nullptr).
// Writes h_out fp32 [64,1024] (which is also the y row for this t).
__global__ __launch_bounds__(256) void gru_step(
    const float* __restrict__ h_in,
    const float* __restrict__ Whh,
    const float* __restrict__ b_hh,
    const float* __restrict__ gx_base,
    const int* __restrict__ xrow,
    float* __restrict__ h_out) {
  __shared__ __align__(16) unsigned short Hh[64][40], Hl[64][40];
  __shared__ __align__(16) unsigned short Wh[48][40], Wl[48][40];

  const int tid = threadIdx.x;
  const int lane = tid & 63, wv = tid >> 6;
  const int j0 = blockIdx.x * 16;  // 64 blocks cover j in [0,1024)

  f32x4 acc[3];
  const f32x4 zero = {0.f, 0.f, 0.f, 0.f};
#pragma unroll
  for (int g = 0; g < 3; ++g) acc[g] = zero;

  const int srow = tid >> 2;        // 0..63 (batch row for H staging)
  const int sseg = (tid & 3) * 8;   // k sub-segment
  const bool wact = (tid < 192);    // W staging: 48 rows x 4 segs
  const int wr = srow;              // 0..47 when wact
  const int wgate = wr >> 4, wj = wr & 15;

  const float* pH = h_in + srow * H + sseg;
  const float* pW = Whh + ((size_t)(wgate * H + j0 + wj)) * H + sseg;

  const int ar = wv * 16 + (lane & 15);
  const int kk = (lane >> 4) * 8;

  // prefetch k0 = 0
  float4 fh0 = *reinterpret_cast<const float4*>(pH);
  float4 fh1 = *reinterpret_cast<const float4*>(pH + 4);
  float4 fw0, fw1;
  if (wact) {
    fw0 = *reinterpret_cast<const float4*>(pW);
    fw1 = *reinterpret_cast<const float4*>(pW + 4);
  }

  for (int k0 = 0; k0 < H; k0 += 32) {
    int4 hH, lH, hW, lW;
    split8(fh0, fh1, hH, lH);
    if (wact) split8(fw0, fw1, hW, lW);
    __syncthreads();
    *reinterpret_cast<int4*>(&Hh[srow][sseg]) = hH;
    *reinterpret_cast<int4*>(&Hl[srow][sseg]) = lH;
    if (wact) {
      *reinterpret_cast<int4*>(&Wh[wr][sseg]) = hW;
      *reinterpret_cast<int4*>(&Wl[wr][sseg]) = lW;
    }
    __syncthreads();
    if (k0 + 32 < H) {  // register prefetch for next k-slice
      fh0 = *reinterpret_cast<const float4*>(pH + k0 + 32);
      fh1 = *reinterpret_cast<const float4*>(pH + k0 + 36);
      if (wact) {
        fw0 = *reinterpret_cast<const float4*>(pW + k0 + 32);
        fw1 = *reinterpret_cast<const float4*>(pW + k0 + 36);
      }
    }

    bf16x8 ah = *reinterpret_cast<const bf16x8*>(&Hh[ar][kk]);
    bf16x8 al = *reinterpret_cast<const bf16x8*>(&Hl[ar][kk]);
#pragma unroll
    for (int g = 0; g < 3; ++g) {
      const int br = g * 16 + (lane & 15);
      bf16x8 bh = *reinterpret_cast<const bf16x8*>(&Wh[br][kk]);
      bf16x8 bl = *reinterpret_cast<const bf16x8*>(&Wl[br][kk]);
      acc[g] = __builtin_amdgcn_mfma_f32_16x16x32_bf16(ah, bh, acc[g], 0, 0, 0);
      acc[g] = __builtin_amdgcn_mfma_f32_16x16x32_bf16(ah, bl, acc[g], 0, 0, 0);
      acc[g] = __builtin_amdgcn_mfma_f32_16x16x32_bf16(al, bh, acc[g], 0, 0, 0);
    }
  }

  // epilogue: gates in fp32
  const int cl = lane & 15;
  const int j = j0 + cl;
  const float bhr = b_hh[j], bhz = b_hh[H + j], bhn = b_hh[2 * H + j];
#pragma unroll
  for (int r = 0; r < 4; ++r) {
    const int b = wv * 16 + (lane >> 4) * 4 + r;
    const float* gx = xrow ? (gx_base + (size_t)xrow[b * T] * G)
                           : (gx_base + (size_t)b * G);
    const float xr = gx[j], xz = gx[H + j], xn = gx[2 * H + j];
    const float ghr = acc[0][r] + bhr;
    const float ghz = acc[1][r] + bhz;
    const float ghn = acc[2][r] + bhn;
    const float rg = 1.f / (1.f + __expf(-(xr + ghr)));
    const float zg = 1.f / (1.f + __expf(-(xz + ghz)));
    const float ng = tanhf(xn + rg * ghn);
    const float hp = h_in[b * H + j];
    h_out[b * H + j] = (1.f - zg) * ng + zg * hp;
  }
}

}  // namespace

// ============================================================================
extern "C" void kernel_launch(void* const* d_in, const int* in_sizes, int n_in,
                              void* d_out, int out_size, void* d_ws, size_t ws_size,
                              hipStream_t stream) {
  const int* X = (const int*)d_in[0];        // [B,T]
  const float* h0 = (const float*)d_in[1];   // [L,B,H]
  const float* emb = (const float*)d_in[2];  // [V,E]
  const float* W_ih = (const float*)d_in[3]; // [L,3H,H]
  const float* W_hh = (const float*)d_in[4]; // [L,3H,H]
  const float* b_ih = (const float*)d_in[5]; // [L,3H]
  const float* b_hh = (const float*)d_in[6]; // [L,3H]
  const float* W_out = (const float*)d_in[7];// [V,H]
  const float* b_out = (const float*)d_in[8];// [V]
  float* out = (float*)d_out;
  (void)in_sizes; (void)n_in; (void)out_size;

  // ---- workspace: G0 (3 MB) + chunk buffers, Tc adaptive to ws_size ----
  auto rup = [](size_t b) { return (b + 255) & ~(size_t)255; };
  const size_t g0_b = rup((size_t)V * G * 4);
  int Tc = 64;
  for (; Tc > 4; Tc >>= 1) {
    size_t need = g0_b + 2 * rup((size_t)Tc * B * H * 4) + rup((size_t)Tc * B * G * 4);
    if (need <= ws_size) break;
  }
  char* p = (char*)d_ws;
  float* G0  = (float*)p;                 p += g0_b;
  float* y1c = (float*)p;                 p += rup((size_t)Tc * B * H * 4);
  float* gx2 = (float*)p;                 p += rup((size_t)Tc * B * G * 4);
  float* y2c = (float*)p;

  // ---- 1. G0 = emb @ W_ih[0]^T + b_ih[0] : [256, 3072] ----
  gemm_bt_f32<0><<<dim3(G / 64, V / 64), 256, 0, stream>>>(
      emb, W_ih, b_ih, G0, V, G, H, 0);

  // ---- 2. chunked: layer-1 steps -> gx2 GEMM -> layer-2 steps -> logits ----
  const int nchunks = T / Tc;
  for (int c = 0; c < nchunks; ++c) {
    const int tcb = c * Tc;

    for (int i = 0; i < Tc; ++i) {  // layer-1 recurrence
      const int t = tcb + i;
      const float* hin = (t == 0) ? h0
                       : (i == 0) ? y1c + (size_t)(Tc - 1) * B * H
                                  : y1c + (size_t)(i - 1) * B * H;
      gru_step<<<64, 256, 0, stream>>>(hin, W_hh, b_hh, G0, X + t,
                                       y1c + (size_t)i * B * H);
    }

    // gx2 = y1c @ W_ih[1]^T + b_ih[1] : [Tc*B, 3072]
    gemm_bt_f32<0><<<dim3(G / 64, (Tc * B) / 64), 256, 0, stream>>>(
        y1c, W_ih + (size_t)G * H, b_ih + G, gx2, Tc * B, G, H, 0);

    for (int i = 0; i < Tc; ++i) {  // layer-2 recurrence
      const int t = tcb + i;
      const float* hin = (t == 0) ? h0 + (size_t)B * H
                       : (i == 0) ? y2c + (size_t)(Tc - 1) * B * H
                                  : y2c + (size_t)(i - 1) * B * H;
      gru_step<<<64, 256, 0, stream>>>(hin, W_hh + (size_t)G * H, b_hh + G,
                                       gx2 + (size_t)i * B * G, nullptr,
                                       y2c + (size_t)i * B * H);
    }

    // logits chunk: y2c @ W_out^T + b_out -> out rows (b*(T-1)+t)
    gemm_bt_f32<2><<<dim3(V / 64, (Tc * B) / 64), 256, 0, stream>>>(
        y2c, W_out, b_out, out, Tc * B, V, H, tcb);
  }
}

// Round 3
// 18032.678 us; speedup vs baseline: 1.6632x; 1.6632x over previous
//
#include <hip/hip_runtime.h>
#include <stdint.h>

// ============================================================================
// CharNN: 2-layer GRU char LM (B=64, T=512, V=256, E=H=1024) on MI355X.
// Round 3 strategy:
//  * W_hh pre-packed ONCE into per-block LDS-image tiles (split bf16 hi/lo,
//    gates r/z/n packed into one 16-row MFMA B-tile, 4 pad rows) -> 64KB/block
//  * h state carried as split bf16 hi/lo in MFMA-gather tile order
//    [k0][b][k] -> A-frags load global->VGPR directly; NO barriers in k-loop
//  * gru_step: 256 blocks (j-tile 4), gates coupled via shfl_xor(4/8)
//  * GEMMs take pre-split hi/lo operands (no split8 in inner loops)
//  * chunked over T (Tc adaptive to ws_size): y1 chunk -> gx2 GEMM -> layer2
// ============================================================================

namespace {

constexpr int B = 64, T = 512, V = 256, H = 1024, G = 3072; // G = 3*H
typedef unsigned short u16;

typedef short bf16x8 __attribute__((ext_vector_type(8)));
typedef float f32x4 __attribute__((ext_vector_type(4)));

__device__ __forceinline__ u16 f2bf(float f) {
  unsigned int u = __float_as_uint(f);
  u += 0x7fffu + ((u >> 16) & 1u);  // RNE
  return (u16)(u >> 16);
}
__device__ __forceinline__ float bf2f(u16 h) {
  return __uint_as_float(((unsigned int)h) << 16);
}

// ---- fp32 -> (hi, lo) bf16 split (row-major arrays) ------------------------
__global__ void split_f32(const float* __restrict__ src, u16* __restrict__ hi,
                          u16* __restrict__ lo, int n4) {
  int i = blockIdx.x * blockDim.x + threadIdx.x;
  if (i >= n4) return;
  float4 v = reinterpret_cast<const float4*>(src)[i];
  ushort4 h, l;
  h.x = f2bf(v.x); l.x = f2bf(v.x - bf2f(h.x));
  h.y = f2bf(v.y); l.y = f2bf(v.y - bf2f(h.y));
  h.z = f2bf(v.z); l.z = f2bf(v.z - bf2f(h.z));
  h.w = f2bf(v.w); l.w = f2bf(v.w - bf2f(h.w));
  reinterpret_cast<ushort4*>(hi)[i] = h;
  reinterpret_cast<ushort4*>(lo)[i] = l;
}

__device__ __forceinline__ void split8(float4 f0, float4 f1, int4& hv, int4& lv) {
  float vv[8] = {f0.x, f0.y, f0.z, f0.w, f1.x, f1.y, f1.z, f1.w};
  union { u16 u[8]; int4 v; } uh, ul;
#pragma unroll
  for (int q = 0; q < 8; ++q) {
    u16 hb = f2bf(vv[q]);
    uh.u[q] = hb;
    ul.u[q] = f2bf(vv[q] - bf2f(hb));
  }
  hv = uh.v; lv = ul.v;
}

// ---- pack W_hh (both layers) into per-block LDS-image tiles ----------------
// dst block bx (256 per layer) owns j-tile [bx*4, bx*4+4); per k0 (32 of them):
//   [hf=hi][row 0..15][k 0..31] then [hf=lo][...]  (1024 elems per k0)
// row 0..3 = r(jj 0..3), 4..7 = z, 8..11 = n, 12..15 = zero pad.
__global__ void pack_whh(const float* __restrict__ Whh, u16* __restrict__ pW) {
  const int id = blockIdx.x * 256 + threadIdx.x;  // 262144 total
  const int row = id & 15, k0 = (id >> 4) & 31, bx = (id >> 9) & 255,
            layer = (id >> 17) & 1;
  const int g = row >> 2, jj = row & 3;
  u16* dst = pW + (((size_t)(layer * 256 + bx) * 32 + k0) * 1024) + row * 32;
  if (g == 3) {
#pragma unroll
    for (int k = 0; k < 32; ++k) { dst[k] = 0; dst[512 + k] = 0; }
  } else {
    const float* src = Whh + ((size_t)layer * G + g * H + bx * 4 + jj) * H + k0 * 32;
#pragma unroll
    for (int k = 0; k < 32; ++k) {
      float v = src[k];
      u16 h = f2bf(v);
      dst[k] = h;
      dst[512 + k] = f2bf(v - bf2f(h));
    }
  }
}

// ---- pack h0 into the h-tile layout [k0][b][k] split hi/lo -----------------
__global__ void pack_h0(const float* __restrict__ h0, u16* __restrict__ h0_hi,
                        u16* __restrict__ h0_lo, u16* __restrict__ h1_hi,
                        u16* __restrict__ h1_lo) {
  const int id = blockIdx.x * 256 + threadIdx.x;  // 131072
  const int layer = id >> 16, b = (id >> 10) & 63, j = id & 1023;
  const float v = h0[id];
  const size_t a = ((size_t)(j >> 5) * 64 + b) * 32 + (j & 31);
  const u16 h = f2bf(v), l = f2bf(v - bf2f(h));
  if (layer == 0) { h0_hi[a] = h; h0_lo[a] = l; }
  else            { h1_hi[a] = h; h1_lo[a] = l; }
}

// ---- split-input GEMM: C[M,N] = A @ B^T + bias (A,B pre-split hi/lo) -------
// MODE 0: C fp32 [M,N]. MODE 2: logits epilogue (m = i*64+b, t = tc+i, t<T-1).
template <int MODE>
__global__ __launch_bounds__(256) void gemm_bt_s(
    const u16* __restrict__ Ahi, const u16* __restrict__ Alo,
    const u16* __restrict__ Bhi, const u16* __restrict__ Blo,
    const float* __restrict__ bias, float* __restrict__ C,
    int M, int N, int K, int tc) {
  __shared__ __align__(16) u16 Ah[64][40], Al[64][40];
  __shared__ __align__(16) u16 Bh[64][40], Bl[64][40];

  const int tid = threadIdx.x;
  const int lane = tid & 63, wv = tid >> 6;
  const int bm = blockIdx.y, bn = blockIdx.x;
  const int srow = tid >> 2, sseg = (tid & 3) * 8;

  const u16* pAh = Ahi + (size_t)(bm * 64 + srow) * K + sseg;
  const u16* pAl = Alo + (size_t)(bm * 64 + srow) * K + sseg;
  const u16* pBh = Bhi + (size_t)(bn * 64 + srow) * K + sseg;
  const u16* pBl = Blo + (size_t)(bn * 64 + srow) * K + sseg;

  f32x4 acc[4];
  const f32x4 zero = {0.f, 0.f, 0.f, 0.f};
#pragma unroll
  for (int nt = 0; nt < 4; ++nt) acc[nt] = zero;

  const int ar = wv * 16 + (lane & 15);
  const int kk = (lane >> 4) * 8;

  for (int k0 = 0; k0 < K; k0 += 32) {
    int4 hA = *reinterpret_cast<const int4*>(pAh + k0);
    int4 lA = *reinterpret_cast<const int4*>(pAl + k0);
    int4 hB = *reinterpret_cast<const int4*>(pBh + k0);
    int4 lB = *reinterpret_cast<const int4*>(pBl + k0);
    __syncthreads();
    *reinterpret_cast<int4*>(&Ah[srow][sseg]) = hA;
    *reinterpret_cast<int4*>(&Al[srow][sseg]) = lA;
    *reinterpret_cast<int4*>(&Bh[srow][sseg]) = hB;
    *reinterpret_cast<int4*>(&Bl[srow][sseg]) = lB;
    __syncthreads();

    bf16x8 ah = *reinterpret_cast<const bf16x8*>(&Ah[ar][kk]);
    bf16x8 al = *reinterpret_cast<const bf16x8*>(&Al[ar][kk]);
#pragma unroll
    for (int nt = 0; nt < 4; ++nt) {
      const int br = nt * 16 + (lane & 15);
      bf16x8 bh = *reinterpret_cast<const bf16x8*>(&Bh[br][kk]);
      bf16x8 bl = *reinterpret_cast<const bf16x8*>(&Bl[br][kk]);
      acc[nt] = __builtin_amdgcn_mfma_f32_16x16x32_bf16(ah, bh, acc[nt], 0, 0, 0);
      acc[nt] = __builtin_amdgcn_mfma_f32_16x16x32_bf16(ah, bl, acc[nt], 0, 0, 0);
      acc[nt] = __builtin_amdgcn_mfma_f32_16x16x32_bf16(al, bh, acc[nt], 0, 0, 0);
    }
  }

  const int rbase = wv * 16 + (lane >> 4) * 4;
  const int cl = lane & 15;
#pragma unroll
  for (int nt = 0; nt < 4; ++nt) {
    const int n = bn * 64 + nt * 16 + cl;
    const float bv = bias[n];
#pragma unroll
    for (int r = 0; r < 4; ++r) {
      const int m = bm * 64 + rbase + r;
      const float v = acc[nt][r] + bv;
      if (MODE == 0) {
        C[(size_t)m * N + n] = v;
      } else {
        const int i = m >> 6, bb = m & 63;
        const int t = tc + i;
        if (t < T - 1) C[((size_t)(bb * (T - 1) + t)) * V + n] = v;
      }
    }
  }
}

// ---- fp32-input split GEMM (used once for G0 = emb @ W_ih0^T + b_ih0) ------
__global__ __launch_bounds__(256) void gemm_bt_f32(
    const float* __restrict__ A, const float* __restrict__ Bm,
    const float* __restrict__ bias, float* __restrict__ C, int M, int N, int K) {
  __shared__ __align__(16) u16 Ah[64][40], Al[64][40];
  __shared__ __align__(16) u16 Bh[64][40], Bl[64][40];
  const int tid = threadIdx.x;
  const int lane = tid & 63, wv = tid >> 6;
  const int bm = blockIdx.y, bn = blockIdx.x;
  const int srow = tid >> 2, sseg = (tid & 3) * 8;
  const float* pA = A + (size_t)(bm * 64 + srow) * K + sseg;
  const float* pB = Bm + (size_t)(bn * 64 + srow) * K + sseg;
  f32x4 acc[4];
  const f32x4 zero = {0.f, 0.f, 0.f, 0.f};
#pragma unroll
  for (int nt = 0; nt < 4; ++nt) acc[nt] = zero;
  const int ar = wv * 16 + (lane & 15);
  const int kk = (lane >> 4) * 8;
  for (int k0 = 0; k0 < K; k0 += 32) {
    float4 a0 = *reinterpret_cast<const float4*>(pA + k0);
    float4 a1 = *reinterpret_cast<const float4*>(pA + k0 + 4);
    float4 b0 = *reinterpret_cast<const float4*>(pB + k0);
    float4 b1 = *reinterpret_cast<const float4*>(pB + k0 + 4);
    int4 hA, lA, hB, lB;
    split8(a0, a1, hA, lA);
    split8(b0, b1, hB, lB);
    __syncthreads();
    *reinterpret_cast<int4*>(&Ah[srow][sseg]) = hA;
    *reinterpret_cast<int4*>(&Al[srow][sseg]) = lA;
    *reinterpret_cast<int4*>(&Bh[srow][sseg]) = hB;
    *reinterpret_cast<int4*>(&Bl[srow][sseg]) = lB;
    __syncthreads();
    bf16x8 ah = *reinterpret_cast<const bf16x8*>(&Ah[ar][kk]);
    bf16x8 al = *reinterpret_cast<const bf16x8*>(&Al[ar][kk]);
#pragma unroll
    for (int nt = 0; nt < 4; ++nt) {
      const int br = nt * 16 + (lane & 15);
      bf16x8 bh = *reinterpret_cast<const bf16x8*>(&Bh[br][kk]);
      bf16x8 bl = *reinterpret_cast<const bf16x8*>(&Bl[br][kk]);
      acc[nt] = __builtin_amdgcn_mfma_f32_16x16x32_bf16(ah, bh, acc[nt], 0, 0, 0);
      acc[nt] = __builtin_amdgcn_mfma_f32_16x16x32_bf16(ah, bl, acc[nt], 0, 0, 0);
      acc[nt] = __builtin_amdgcn_mfma_f32_16x16x32_bf16(al, bh, acc[nt], 0, 0, 0);
    }
  }
  const int rbase = wv * 16 + (lane >> 4) * 4;
  const int cl = lane & 15;
#pragma unroll
  for (int nt = 0; nt < 4; ++nt) {
    const int n = bn * 64 + nt * 16 + cl;
    const float bv = bias[n];
#pragma unroll
    for (int r = 0; r < 4; ++r) {
      const int m = bm * 64 + rbase + r;
      C[(size_t)m * N + n] = acc[nt][r] + bv;
    }
  }
}

// ---- GRU step v3 -----------------------------------------------------------
// 256 blocks x 256 threads. Block bx owns j-tile [bx*4, bx*4+4).
// pW: this layer's packed W (block-major, 32768 u16 per block).
// hin/hout: h state tiles [k0][b][k] split hi/lo.
// gx: layer1 -> G0 [256,3072] via xrow[b*T] (xrow = X+t); layer2 -> rows per b.
// yr: row-major split y output for chunk GEMMs (yr_hi[b*H+j]).
__global__ __launch_bounds__(256) void gru_step3(
    const u16* __restrict__ pW,
    const u16* __restrict__ hin_hi, const u16* __restrict__ hin_lo,
    u16* __restrict__ hout_hi, u16* __restrict__ hout_lo,
    const float* __restrict__ b_hh,
    const float* __restrict__ gx_base, const int* __restrict__ xrow,
    u16* __restrict__ yr_hi, u16* __restrict__ yr_lo) {
  __shared__ __align__(16) u16 Wt[32768];  // 64 KB: [k0][hf][row16][k32]

  const int tid = threadIdx.x;
  const int lane = tid & 63, wv = tid >> 6;
  const int l15 = lane & 15, kq = lane >> 4;

  // ---- stage W once (pipelined burst; single barrier) ----
  {
    const int4* src = reinterpret_cast<const int4*>(pW + (size_t)blockIdx.x * 32768);
    int4* dst = reinterpret_cast<int4*>(Wt);
#pragma unroll
    for (int i = 0; i < 16; ++i) dst[i * 256 + tid] = src[i * 256 + tid];
  }
  __syncthreads();

  // ---- barrier-free k-loop: A-frags straight from global h tiles ----
  const u16* pa_hi = hin_hi + (wv * 16 + l15) * 32 + kq * 8;
  const u16* pa_lo = hin_lo + (wv * 16 + l15) * 32 + kq * 8;
  const u16* wt = Wt + l15 * 32 + kq * 8;

  f32x4 acc = {0.f, 0.f, 0.f, 0.f};
#pragma unroll 8
  for (int k0 = 0; k0 < 32; ++k0) {
    bf16x8 ah = *reinterpret_cast<const bf16x8*>(pa_hi + k0 * 2048);
    bf16x8 al = *reinterpret_cast<const bf16x8*>(pa_lo + k0 * 2048);
    bf16x8 bh = *reinterpret_cast<const bf16x8*>(wt + k0 * 1024);
    bf16x8 bl = *reinterpret_cast<const bf16x8*>(wt + k0 * 1024 + 512);
    acc = __builtin_amdgcn_mfma_f32_16x16x32_bf16(ah, bh, acc, 0, 0, 0);
    acc = __builtin_amdgcn_mfma_f32_16x16x32_bf16(ah, bl, acc, 0, 0, 0);
    acc = __builtin_amdgcn_mfma_f32_16x16x32_bf16(al, bh, acc, 0, 0, 0);
  }

  // ---- epilogue: cols 0..3 = r, 4..7 = z, 8..11 = n (shfl couples gates) ----
  float gz[4], gn[4];
#pragma unroll
  for (int r = 0; r < 4; ++r) {
    gz[r] = __shfl_xor(acc[r], 4);
    gn[r] = __shfl_xor(acc[r], 8);
  }
  const int jj = l15;
  if (jj < 4) {
    const int j = blockIdx.x * 4 + jj;
    const float bhr = b_hh[j], bhz = b_hh[H + j], bhn = b_hh[2 * H + j];
    const size_t tb = (size_t)(j >> 5) * 2048 + (j & 31);
#pragma unroll
    for (int r = 0; r < 4; ++r) {
      const int b = wv * 16 + kq * 4 + r;
      const float* gx = xrow ? (gx_base + (size_t)xrow[b * T] * G)
                             : (gx_base + (size_t)b * G);
      const float xr = gx[j], xz = gx[H + j], xn = gx[2 * H + j];
      const size_t ha = tb + (size_t)b * 32;
      const float hp = bf2f(hin_hi[ha]) + bf2f(hin_lo[ha]);
      const float rg = 1.f / (1.f + __expf(-(xr + acc[r] + bhr)));
      const float zg = 1.f / (1.f + __expf(-(xz + gz[r] + bhz)));
      const float ng = tanhf(xn + rg * (gn[r] + bhn));
      const float hv = (1.f - zg) * ng + zg * hp;
      const u16 hh = f2bf(hv), hl = f2bf(hv - bf2f(hh));
      hout_hi[ha] = hh; hout_lo[ha] = hl;
      yr_hi[(size_t)b * H + j] = hh; yr_lo[(size_t)b * H + j] = hl;
    }
  }
}

}  // namespace

// ============================================================================
extern "C" void kernel_launch(void* const* d_in, const int* in_sizes, int n_in,
                              void* d_out, int out_size, void* d_ws, size_t ws_size,
                              hipStream_t stream) {
  const int* X = (const int*)d_in[0];
  const float* h0 = (const float*)d_in[1];
  const float* emb = (const float*)d_in[2];
  const float* W_ih = (const float*)d_in[3];
  const float* W_hh = (const float*)d_in[4];
  const float* b_ih = (const float*)d_in[5];
  const float* b_hh = (const float*)d_in[6];
  const float* W_out = (const float*)d_in[7];
  const float* b_out = (const float*)d_in[8];
  float* out = (float*)d_out;
  (void)in_sizes; (void)n_in; (void)out_size;

  auto rup = [](size_t b) { return (b + 255) & ~(size_t)255; };
  // fixed allocations
  const size_t pW_b   = (size_t)2 * 256 * 32768 * 2;        // 32 MB packed W_hh
  const size_t G0_b   = rup((size_t)V * G * 4);             // 3 MB
  const size_t wih2_b = rup((size_t)G * H * 2);             // 6 MB each (hi/lo)
  const size_t wout_b = rup((size_t)V * H * 2);
  const size_t ph_b   = rup((size_t)B * H * 2);             // 128 KB per buffer
  size_t fixed = pW_b + G0_b + 2 * wih2_b + 2 * wout_b + 8 * ph_b;
  // per-Tc: y1 hi/lo + y2 hi/lo + gx2 fp32
  int Tc = 64;
  for (; Tc > 2; Tc >>= 1) {
    size_t need = fixed + 4 * rup((size_t)Tc * B * H * 2) + rup((size_t)Tc * B * G * 4);
    if (need <= ws_size) break;
  }
  char* p = (char*)d_ws;
  auto alloc = [&](size_t bytes) { char* q = p; p += rup(bytes); return q; };
  u16* pWhh   = (u16*)alloc(pW_b);
  float* G0   = (float*)alloc(G0_b);
  u16* wih2_h = (u16*)alloc(wih2_b);
  u16* wih2_l = (u16*)alloc(wih2_b);
  u16* wout_h = (u16*)alloc(wout_b);
  u16* wout_l = (u16*)alloc(wout_b);
  u16* ph_hi[2][2], *ph_lo[2][2];
  for (int ly = 0; ly < 2; ++ly)
    for (int pp = 0; pp < 2; ++pp) {
      ph_hi[ly][pp] = (u16*)alloc(ph_b);
      ph_lo[ly][pp] = (u16*)alloc(ph_b);
    }
  u16* y1_hi = (u16*)alloc((size_t)Tc * B * H * 2);
  u16* y1_lo = (u16*)alloc((size_t)Tc * B * H * 2);
  u16* y2_hi = (u16*)alloc((size_t)Tc * B * H * 2);
  u16* y2_lo = (u16*)alloc((size_t)Tc * B * H * 2);
  float* gx2 = (float*)alloc((size_t)Tc * B * G * 4);

  // ---- one-time packs / splits / G0 ----
  pack_whh<<<1024, 256, 0, stream>>>(W_hh, pWhh);
  pack_h0<<<512, 256, 0, stream>>>(h0, ph_hi[0][0], ph_lo[0][0],
                                   ph_hi[1][0], ph_lo[1][0]);
  split_f32<<<(G * H / 4 + 255) / 256, 256, 0, stream>>>(
      W_ih + (size_t)G * H, wih2_h, wih2_l, G * H / 4);
  split_f32<<<(V * H / 4 + 255) / 256, 256, 0, stream>>>(
      W_out, wout_h, wout_l, V * H / 4);
  gemm_bt_f32<<<dim3(G / 64, V / 64), 256, 0, stream>>>(
      emb, W_ih, b_ih, G0, V, G, H);

  // ---- chunked recurrence ----
  const int nchunks = T / Tc;
  for (int c = 0; c < nchunks; ++c) {
    const int tcb = c * Tc;

    for (int i = 0; i < Tc; ++i) {  // layer 1
      const int t = tcb + i;
      gru_step3<<<256, 256, 0, stream>>>(
          pWhh, ph_hi[0][t & 1], ph_lo[0][t & 1],
          ph_hi[0][(t + 1) & 1], ph_lo[0][(t + 1) & 1],
          b_hh, G0, X + t,
          y1_hi + (size_t)i * B * H, y1_lo + (size_t)i * B * H);
    }

    // gx2 = y1 @ W_ih[1]^T + b_ih[1]
    gemm_bt_s<0><<<dim3(G / 64, Tc), 256, 0, stream>>>(
        y1_hi, y1_lo, wih2_h, wih2_l, b_ih + G, gx2, Tc * B, G, H, 0);

    for (int i = 0; i < Tc; ++i) {  // layer 2
      const int t = tcb + i;
      gru_step3<<<256, 256, 0, stream>>>(
          pWhh + (size_t)256 * 32768, ph_hi[1][t & 1], ph_lo[1][t & 1],
          ph_hi[1][(t + 1) & 1], ph_lo[1][(t + 1) & 1],
          b_hh + G, gx2 + (size_t)i * B * G, nullptr,
          y2_hi + (size_t)i * B * H, y2_lo + (size_t)i * B * H);
    }

    // logits chunk
    gemm_bt_s<2><<<dim3(V / 64, Tc), 256, 0, stream>>>(
        y2_hi, y2_lo, wout_h, wout_l, b_out, out, Tc * B, V, H, tcb);
  }
}